// Round 5
// baseline (478.379 us; speedup 1.0000x reference)
//
#include <hip/hip_runtime.h>
#include <hip/hip_fp16.h>
#include <type_traits>

#define NFEAT 128
// Node ids must fit 17 bits for the packed bucket entry (N=100000 < 2^17).
#define SRC_BITS 17
#define SRC_MASK ((1u << SRC_BITS) - 1u)

static inline size_t align_up(size_t x, size_t a) { return (x + a - 1) & ~(a - 1); }

// ---------------- preprocessing ----------------

// per-node in-degree + per-(bucket, vblk) sub-counts (vblk = blockIdx&7 ~ XCD affinity)
__global__ __launch_bounds__(256) void k_count2(const int* __restrict__ dst,
                                                int* __restrict__ cnt,
                                                int* __restrict__ sb, int E) {
  int e = blockIdx.x * 256 + threadIdx.x;
  if (e >= E) return;
  int d = dst[e];
  atomicAdd(&cnt[d], 1);
  atomicAdd(&sb[((d >> 6) << 3) | (blockIdx.x & 7)], 1);
}

// block-level exclusive scan, 1024 items/block (256 thr x 4)
__global__ __launch_bounds__(256) void k_scan1(const int* __restrict__ cnt,
                                               int* __restrict__ rs,
                                               int* __restrict__ bsums, int N) {
  __shared__ int sd[256];
  int tid = threadIdx.x;
  int base = blockIdx.x * 1024 + tid * 4;
  int v0 = 0, v1 = 0, v2 = 0, v3 = 0;
  if (base + 0 < N) v0 = cnt[base + 0];
  if (base + 1 < N) v1 = cnt[base + 1];
  if (base + 2 < N) v2 = cnt[base + 2];
  if (base + 3 < N) v3 = cnt[base + 3];
  int sum = v0 + v1 + v2 + v3;
  sd[tid] = sum;
  __syncthreads();
  for (int off = 1; off < 256; off <<= 1) {
    int t = (tid >= off) ? sd[tid - off] : 0;
    __syncthreads();
    sd[tid] += t;
    __syncthreads();
  }
  int run = sd[tid] - sum;
  if (tid == 255) bsums[blockIdx.x] = sd[255];
  if (base + 0 < N) rs[base + 0] = run;
  run += v0;
  if (base + 1 < N) rs[base + 1] = run;
  run += v1;
  if (base + 2 < N) rs[base + 2] = run;
  run += v2;
  if (base + 3 < N) rs[base + 3] = run;
}

__global__ __launch_bounds__(128) void k_scan2(int* bsums, int nb) {
  __shared__ int sd[128];
  int tid = threadIdx.x;
  int v = (tid < nb) ? bsums[tid] : 0;
  sd[tid] = v;
  __syncthreads();
  for (int off = 1; off < 128; off <<= 1) {
    int t = (tid >= off) ? sd[tid - off] : 0;
    __syncthreads();
    sd[tid] += t;
    __syncthreads();
  }
  if (tid < nb) bsums[tid] = sd[tid] - v;
}

__global__ __launch_bounds__(256) void k_scan3(int* __restrict__ rs,
                                               const int* __restrict__ bsums,
                                               int N, int E) {
  int i = blockIdx.x * 256 + threadIdx.x;
  if (i < N) rs[i] += bsums[i >> 10];
  if (i == 0) rs[N] = E;
}

// turn sub-counts into append cursors: bucket base rs[b<<6] + exclusive prefix over 8 vblks
__global__ __launch_bounds__(256) void k_sofs(const int* __restrict__ rs,
                                              int* __restrict__ sb, int NB) {
  for (int b = threadIdx.x; b < NB; b += 256) {
    int run = rs[b << 6];
    #pragma unroll
    for (int k = 0; k < 8; ++k) {
      int c = sb[(b << 3) | k];
      sb[(b << 3) | k] = run;
      run += c;
    }
  }
}

// append packed (dst&63)<<17 | src into the edge's (bucket, vblk) sub-region.
// Sub-region is written only by blocks with equal blockIdx&7 -> same XCD (round-robin
// dispatch) -> consecutive appends coalesce in one L2 -> writes ~= payload.
__global__ __launch_bounds__(256) void k_bucket(const int* __restrict__ src,
                                                const int* __restrict__ dst,
                                                int* __restrict__ sb,
                                                unsigned* __restrict__ ebuf, int E) {
  int e = blockIdx.x * 256 + threadIdx.x;
  if (e >= E) return;
  int d = dst[e];
  int pos = atomicAdd(&sb[((d >> 6) << 3) | (blockIdx.x & 7)], 1);
  ebuf[pos] = (unsigned)src[e] | ((unsigned)(d & 63) << SRC_BITS);
}

// exact CSR within each bucket: one block per bucket, LDS cursors, block-owned csrc range
__global__ __launch_bounds__(256) void k_fill2(const unsigned* __restrict__ ebuf,
                                               const int* __restrict__ rs,
                                               int* __restrict__ csrc, int N) {
  __shared__ int lcur[64];
  int b = blockIdx.x;
  int node0 = b << 6;
  int nn = min(64, N - node0);
  if (threadIdx.x < nn) lcur[threadIdx.x] = rs[node0 + threadIdx.x];
  __syncthreads();
  int e0 = rs[node0];
  int e1 = rs[node0 + nn];
  for (int e = e0 + threadIdx.x; e < e1; e += 256) {
    unsigned u = ebuf[e];
    int pos = atomicAdd(&lcur[u >> SRC_BITS], 1);
    csrc[pos] = (int)(u & SRC_MASK);
  }
}

// ---------------- GEMM: P[N x128] = dis[i] * (X[N x128] @ W[128 x128]), fp16 out ----------------

template <typename T>
__global__ __launch_bounds__(256) void k_gemm(const T* __restrict__ X,
                                              const float* __restrict__ W,
                                              const int* __restrict__ deg,
                                              __half* __restrict__ P, int N) {
  __shared__ float Xs[64][132];   // +4 pad
  __shared__ float Ws[64][128];
  const int tid = threadIdx.x;
  const int rowBase = blockIdx.x * 64;

  if constexpr (std::is_same_v<T, float>) {
    #pragma unroll
    for (int it = 0; it < 8; ++it) {
      int q = it * 256 + tid;
      int r = q >> 5;
      int c = (q & 31) * 4;
      int gr = rowBase + r;
      float4 v = make_float4(0.f, 0.f, 0.f, 0.f);
      if (gr < N) v = *(const float4*)(X + (size_t)gr * NFEAT + c);
      *(float4*)&Xs[r][c] = v;
    }
  } else {
    #pragma unroll
    for (int it = 0; it < 4; ++it) {
      int q = it * 256 + tid;
      int r = q >> 4;
      int c = (q & 15) * 8;
      int gr = rowBase + r;
      int4 raw = make_int4(0, 0, 0, 0);
      if (gr < N) raw = *(const int4*)(X + (size_t)gr * NFEAT + c);
      const __half2* h2 = (const __half2*)&raw;
      #pragma unroll
      for (int j = 0; j < 4; ++j) {
        float2 f = __half22float2(h2[j]);
        Xs[r][c + 2 * j] = f.x;
        Xs[r][c + 2 * j + 1] = f.y;
      }
    }
  }

  float acc[4][8];
  #pragma unroll
  for (int j = 0; j < 4; ++j)
    #pragma unroll
    for (int c = 0; c < 8; ++c) acc[j][c] = 0.f;

  const int cx = (tid & 15) * 8;
  const int r0 = (tid >> 4) * 4;

  for (int half = 0; half < 2; ++half) {
    __syncthreads();
    #pragma unroll
    for (int it = 0; it < 8; ++it) {
      int q = it * 256 + tid;
      int r = q >> 5;
      int c = (q & 31) * 4;
      *(float4*)&Ws[r][c] = *(const float4*)(W + (size_t)(half * 64 + r) * NFEAT + c);
    }
    __syncthreads();
    #pragma unroll 4
    for (int k = 0; k < 64; ++k) {
      float4 w0 = *(const float4*)&Ws[k][cx];
      float4 w1 = *(const float4*)&Ws[k][cx + 4];
      int kg = half * 64 + k;
      #pragma unroll
      for (int j = 0; j < 4; ++j) {
        float xv = Xs[r0 + j][kg];
        acc[j][0] = fmaf(xv, w0.x, acc[j][0]);
        acc[j][1] = fmaf(xv, w0.y, acc[j][1]);
        acc[j][2] = fmaf(xv, w0.z, acc[j][2]);
        acc[j][3] = fmaf(xv, w0.w, acc[j][3]);
        acc[j][4] = fmaf(xv, w1.x, acc[j][4]);
        acc[j][5] = fmaf(xv, w1.y, acc[j][5]);
        acc[j][6] = fmaf(xv, w1.z, acc[j][6]);
        acc[j][7] = fmaf(xv, w1.w, acc[j][7]);
      }
    }
  }

  #pragma unroll
  for (int j = 0; j < 4; ++j) {
    int gr = rowBase + r0 + j;
    if (gr < N) {
      float di = rsqrtf((float)deg[gr] + 1.0f);
      __half2 o[4];
      o[0] = __floats2half2_rn(di * acc[j][0], di * acc[j][1]);
      o[1] = __floats2half2_rn(di * acc[j][2], di * acc[j][3]);
      o[2] = __floats2half2_rn(di * acc[j][4], di * acc[j][5]);
      o[3] = __floats2half2_rn(di * acc[j][6], di * acc[j][7]);
      *(int4*)(P + (size_t)gr * NFEAT + cx) = *(const int4*)o;
    }
  }
}

// ---------------- aggregation: one wave/node, 4 edge-groups x 16 lanes, 16B/lane ----------------

__device__ __forceinline__ float agg_body(const __half* __restrict__ P,
                                          const int* __restrict__ rs,
                                          const int* __restrict__ csrc,
                                          int w, int g, int li, float acc[8]) {
  int e0 = rs[w], e1 = rs[w + 1];
  float di = rsqrtf((float)(e1 - e0) + 1.0f);
  if (g == 0) {  // self loop: P'[w]
    int4 raw = *(const int4*)(P + (size_t)w * NFEAT + li * 8);
    const __half2* h2 = (const __half2*)&raw;
    #pragma unroll
    for (int j = 0; j < 4; ++j) {
      float2 f = __half22float2(h2[j]);
      acc[2 * j]     = f.x;
      acc[2 * j + 1] = f.y;
    }
  }
  int e = e0 + g;
  int s = (e < e1) ? csrc[e] : 0;  // prefetched index
  while (e < e1) {
    int4 raw = *(const int4*)(P + (size_t)s * NFEAT + li * 8);
    e += 4;
    s = csrc[min(e, e1 - 1)];      // branchless prefetch of next index
    const __half2* h2 = (const __half2*)&raw;
    #pragma unroll
    for (int j = 0; j < 4; ++j) {
      float2 f = __half22float2(h2[j]);
      acc[2 * j]     += f.x;
      acc[2 * j + 1] += f.y;
    }
  }
  #pragma unroll
  for (int j = 0; j < 8; ++j) {
    float v = acc[j];
    v += __shfl_xor(v, 16, 64);
    v += __shfl_xor(v, 32, 64);
    acc[j] = v;
  }
  return di;
}

__global__ __launch_bounds__(256) void k_agg_relu(const __half* __restrict__ P,
                                                  const int* __restrict__ rs,
                                                  const int* __restrict__ csrc,
                                                  const float* __restrict__ bias,
                                                  __half* __restrict__ Hout, int N) {
  int w = (blockIdx.x * 256 + threadIdx.x) >> 6;
  if (w >= N) return;
  int lane = threadIdx.x & 63;
  int g = lane >> 4, li = lane & 15;
  float acc[8] = {0, 0, 0, 0, 0, 0, 0, 0};
  float di = agg_body(P, rs, csrc, w, g, li, acc);
  if (g == 0) {
    float4 b0 = *(const float4*)(bias + li * 8);
    float4 b1 = *(const float4*)(bias + li * 8 + 4);
    __half2 o[4];
    o[0] = __floats2half2_rn(fmaxf(fmaf(di, acc[0], b0.x), 0.f),
                             fmaxf(fmaf(di, acc[1], b0.y), 0.f));
    o[1] = __floats2half2_rn(fmaxf(fmaf(di, acc[2], b0.z), 0.f),
                             fmaxf(fmaf(di, acc[3], b0.w), 0.f));
    o[2] = __floats2half2_rn(fmaxf(fmaf(di, acc[4], b1.x), 0.f),
                             fmaxf(fmaf(di, acc[5], b1.y), 0.f));
    o[3] = __floats2half2_rn(fmaxf(fmaf(di, acc[6], b1.z), 0.f),
                             fmaxf(fmaf(di, acc[7], b1.w), 0.f));
    *(int4*)(Hout + (size_t)w * NFEAT + li * 8) = *(const int4*)o;
  }
}

__global__ __launch_bounds__(256) void k_agg_readout(const __half* __restrict__ P,
                                                     const int* __restrict__ rs,
                                                     const int* __restrict__ csrc,
                                                     const float* __restrict__ bias,
                                                     const float* __restrict__ Wout,
                                                     const float* __restrict__ bout,
                                                     float* __restrict__ out, int N) {
  int w = (blockIdx.x * 256 + threadIdx.x) >> 6;
  if (w >= N) return;
  int lane = threadIdx.x & 63;
  int g = lane >> 4, li = lane & 15;
  float acc[8] = {0, 0, 0, 0, 0, 0, 0, 0};
  float di = agg_body(P, rs, csrc, w, g, li, acc);
  float4 b0 = *(const float4*)(bias + li * 8);
  float4 b1 = *(const float4*)(bias + li * 8 + 4);
  float4 w0 = *(const float4*)(Wout + li * 8);
  float4 w1 = *(const float4*)(Wout + li * 8 + 4);
  float p = 0.f;
  p = fmaf(fmaxf(fmaf(di, acc[0], b0.x), 0.f), w0.x, p);
  p = fmaf(fmaxf(fmaf(di, acc[1], b0.y), 0.f), w0.y, p);
  p = fmaf(fmaxf(fmaf(di, acc[2], b0.z), 0.f), w0.z, p);
  p = fmaf(fmaxf(fmaf(di, acc[3], b0.w), 0.f), w0.w, p);
  p = fmaf(fmaxf(fmaf(di, acc[4], b1.x), 0.f), w1.x, p);
  p = fmaf(fmaxf(fmaf(di, acc[5], b1.y), 0.f), w1.y, p);
  p = fmaf(fmaxf(fmaf(di, acc[6], b1.z), 0.f), w1.z, p);
  p = fmaf(fmaxf(fmaf(di, acc[7], b1.w), 0.f), w1.w, p);
  p += __shfl_down(p, 8, 64);
  p += __shfl_down(p, 4, 64);
  p += __shfl_down(p, 2, 64);
  p += __shfl_down(p, 1, 64);
  if (lane == 0) out[w] = p + bout[0];
}

// ---------------- launch ----------------

extern "C" void kernel_launch(void* const* d_in, const int* in_sizes, int n_in,
                              void* d_out, int out_size, void* d_ws, size_t ws_size,
                              hipStream_t stream) {
  const float* x    = (const float*)d_in[0];
  const int*   ei   = (const int*)d_in[1];
  const float* W1   = (const float*)d_in[2];
  const float* b1   = (const float*)d_in[3];
  const float* W2   = (const float*)d_in[4];
  const float* b2   = (const float*)d_in[5];
  const float* Wout = (const float*)d_in[6];
  const float* bout = (const float*)d_in[7];
  float* out = (float*)d_out;

  const int N = in_sizes[0] / NFEAT;
  const int E = in_sizes[1] / 2;
  const int* src = ei;
  const int* dst = ei + E;
  const int NB = (N + 63) >> 6;  // buckets of 64 nodes

  char* ws = (char*)d_ws;
  size_t off = 0;
  auto alloc = [&](size_t bytes) -> char* {
    char* p = ws + off;
    off = align_up(off + bytes, 256);
    return p;
  };
  int*      cnt   = (int*)alloc((size_t)N * 4);          // in-degree (epilogue dis)
  int*      rs    = (int*)alloc((size_t)(N + 1) * 4);
  int*      bsums = (int*)alloc(1024 * 4);
  int*      sb    = (int*)alloc((size_t)NB * 8 * 4);     // sub-counts -> append cursors
  unsigned* ebuf  = (unsigned*)alloc((size_t)E * 4);     // bucket-grouped packed edges
  int*      csrc  = (int*)alloc((size_t)E * 4);
  __half*   P     = (__half*)alloc((size_t)N * NFEAT * 2);
  __half*   H     = (__half*)alloc((size_t)N * NFEAT * 2);
  (void)ws_size; (void)n_in; (void)out_size;

  const int nbN = (N + 255) / 256;
  const int nbE = (E + 255) / 256;
  const int nbS = (N + 1023) / 1024;

  hipMemsetAsync(cnt, 0, (size_t)N * 4, stream);
  hipMemsetAsync(sb, 0, (size_t)NB * 8 * 4, stream);
  k_count2<<<nbE, 256, 0, stream>>>(dst, cnt, sb, E);
  k_scan1<<<nbS, 256, 0, stream>>>(cnt, rs, bsums, N);
  k_scan2<<<1, 128, 0, stream>>>(bsums, nbS);
  k_scan3<<<nbN, 256, 0, stream>>>(rs, bsums, N, E);
  k_sofs<<<1, 256, 0, stream>>>(rs, sb, NB);
  k_bucket<<<nbE, 256, 0, stream>>>(src, dst, sb, ebuf, E);
  k_fill2<<<NB, 256, 0, stream>>>(ebuf, rs, csrc, N);

  k_gemm<float><<<(N + 63) / 64, 256, 0, stream>>>(x, W1, cnt, P, N);
  k_agg_relu<<<(N + 3) / 4, 256, 0, stream>>>(P, rs, csrc, b1, H, N);
  k_gemm<__half><<<(N + 63) / 64, 256, 0, stream>>>(H, W2, cnt, P, N);
  k_agg_readout<<<(N + 3) / 4, 256, 0, stream>>>(P, rs, csrc, b2, Wout, bout, out, N);
}

// Round 6
// 413.091 us; speedup vs baseline: 1.1580x; 1.1580x over previous
//
#include <hip/hip_runtime.h>
#include <hip/hip_fp16.h>
#include <type_traits>

#define NFEAT 128
// Node ids must fit 17 bits for the packed bucket entry (N=100000 < 2^17).
#define SRC_BITS 17
#define SRC_MASK ((1u << SRC_BITS) - 1u)

static inline size_t align_up(size_t x, size_t a) { return (x + a - 1) & ~(a - 1); }

// ---------------- preprocessing ----------------
// Plane-major sub-counters: sb[plane*NB + bucket], plane = blockIdx&7.
// Round-robin dispatch => one XCD per plane => atomic lines stay in that XCD's L2.

__global__ __launch_bounds__(256) void k_count_sb(const int* __restrict__ dst,
                                                  int* __restrict__ sb,
                                                  int NB, int E) {
  int e = blockIdx.x * 256 + threadIdx.x;
  if (e >= E) return;
  atomicAdd(&sb[(blockIdx.x & 7) * NB + (dst[e] >> 6)], 1);
}

// exclusive scan over the NB*8 sub-counts in (bucket-major, plane-minor) logical order;
// also emits bucket bases rsB[0..NB].
__global__ __launch_bounds__(256) void k_scan_sb(int* __restrict__ sb,
                                                 int* __restrict__ rsB,
                                                 int NB, int E) {
  __shared__ int sd[256];
  const int M = NB * 8;
  const int chunk = (M + 255) / 256;
  int tid = threadIdx.x;
  int q0 = tid * chunk;
  int q1 = min(q0 + chunk, M);
  int sum = 0;
  for (int q = q0; q < q1; ++q) sum += sb[(q & 7) * NB + (q >> 3)];
  sd[tid] = sum;
  __syncthreads();
  for (int off = 1; off < 256; off <<= 1) {
    int t = (tid >= off) ? sd[tid - off] : 0;
    __syncthreads();
    sd[tid] += t;
    __syncthreads();
  }
  int run = sd[tid] - sum;
  for (int q = q0; q < q1; ++q) {
    int idx = (q & 7) * NB + (q >> 3);
    int c = sb[idx];
    sb[idx] = run;
    if ((q & 7) == 0) rsB[q >> 3] = run;
    run += c;
  }
  if (tid == 0) rsB[NB] = E;
}

// append packed (dst&63)<<17 | src into the edge's (bucket, plane) sub-region
__global__ __launch_bounds__(256) void k_bucket(const int* __restrict__ src,
                                                const int* __restrict__ dst,
                                                int* __restrict__ sb,
                                                unsigned* __restrict__ ebuf,
                                                int NB, int E) {
  int e = blockIdx.x * 256 + threadIdx.x;
  if (e >= E) return;
  int d = dst[e];
  int pos = atomicAdd(&sb[(blockIdx.x & 7) * NB + (d >> 6)], 1);
  ebuf[pos] = (unsigned)src[e] | ((unsigned)(d & 63) << SRC_BITS);
}

// per-bucket CSR build: LDS histogram -> rs + dis, LDS cursors -> csrc.
// One block per 64-node bucket; all its global writes are block-owned.
__global__ __launch_bounds__(256) void k_fill3(const unsigned* __restrict__ ebuf,
                                               const int* __restrict__ rsB,
                                               int* __restrict__ rs,
                                               float* __restrict__ dis,
                                               int* __restrict__ csrc, int N) {
  __shared__ int hist[64];
  __shared__ int curs[64];
  int b = blockIdx.x;
  int node0 = b << 6;
  int nn = min(64, N - node0);
  int base = rsB[b], end = rsB[b + 1];
  int tid = threadIdx.x;
  if (tid < 64) hist[tid] = 0;
  __syncthreads();
  for (int e = base + tid; e < end; e += 256)
    atomicAdd(&hist[ebuf[e] >> SRC_BITS], 1);
  __syncthreads();
  if (tid == 0) {  // serial 64-entry exclusive scan (trivial)
    int run = base;
    #pragma unroll
    for (int i = 0; i < 64; ++i) {
      int c = hist[i];
      curs[i] = run;
      hist[i] = run;  // hist now holds rs value (start offset)
      run += c;
    }
  }
  __syncthreads();
  if (tid < nn) {
    int start = hist[tid];
    int nxt = (tid == nn - 1) ? end : hist[tid + 1];
    rs[node0 + tid] = start;
    dis[node0 + tid] = rsqrtf((float)(nxt - start) + 1.0f);
  }
  if (tid == 0) rs[node0 + nn] = end;  // rs[N]=E on last bucket; benign dup otherwise
  for (int e = base + tid; e < end; e += 256) {
    unsigned u = ebuf[e];
    int pos = atomicAdd(&curs[u >> SRC_BITS], 1);
    csrc[pos] = (int)(u & SRC_MASK);
  }
}

// ---------------- GEMM: P[N x128] = dis[i] * (X[N x128] @ W[128 x128]), fp16 out ----------------

template <typename T>
__global__ __launch_bounds__(256) void k_gemm(const T* __restrict__ X,
                                              const float* __restrict__ W,
                                              const float* __restrict__ dis,
                                              __half* __restrict__ P, int N) {
  __shared__ float Xs[64][132];   // +4 pad
  __shared__ float Ws[64][128];
  const int tid = threadIdx.x;
  const int rowBase = blockIdx.x * 64;

  if constexpr (std::is_same_v<T, float>) {
    #pragma unroll
    for (int it = 0; it < 8; ++it) {
      int q = it * 256 + tid;
      int r = q >> 5;
      int c = (q & 31) * 4;
      int gr = rowBase + r;
      float4 v = make_float4(0.f, 0.f, 0.f, 0.f);
      if (gr < N) v = *(const float4*)(X + (size_t)gr * NFEAT + c);
      *(float4*)&Xs[r][c] = v;
    }
  } else {
    #pragma unroll
    for (int it = 0; it < 4; ++it) {
      int q = it * 256 + tid;
      int r = q >> 4;
      int c = (q & 15) * 8;
      int gr = rowBase + r;
      int4 raw = make_int4(0, 0, 0, 0);
      if (gr < N) raw = *(const int4*)(X + (size_t)gr * NFEAT + c);
      const __half2* h2 = (const __half2*)&raw;
      #pragma unroll
      for (int j = 0; j < 4; ++j) {
        float2 f = __half22float2(h2[j]);
        Xs[r][c + 2 * j] = f.x;
        Xs[r][c + 2 * j + 1] = f.y;
      }
    }
  }

  float acc[4][8];
  #pragma unroll
  for (int j = 0; j < 4; ++j)
    #pragma unroll
    for (int c = 0; c < 8; ++c) acc[j][c] = 0.f;

  const int cx = (tid & 15) * 8;
  const int r0 = (tid >> 4) * 4;

  for (int half = 0; half < 2; ++half) {
    __syncthreads();
    #pragma unroll
    for (int it = 0; it < 8; ++it) {
      int q = it * 256 + tid;
      int r = q >> 5;
      int c = (q & 31) * 4;
      *(float4*)&Ws[r][c] = *(const float4*)(W + (size_t)(half * 64 + r) * NFEAT + c);
    }
    __syncthreads();
    #pragma unroll 4
    for (int k = 0; k < 64; ++k) {
      float4 w0 = *(const float4*)&Ws[k][cx];
      float4 w1 = *(const float4*)&Ws[k][cx + 4];
      int kg = half * 64 + k;
      #pragma unroll
      for (int j = 0; j < 4; ++j) {
        float xv = Xs[r0 + j][kg];
        acc[j][0] = fmaf(xv, w0.x, acc[j][0]);
        acc[j][1] = fmaf(xv, w0.y, acc[j][1]);
        acc[j][2] = fmaf(xv, w0.z, acc[j][2]);
        acc[j][3] = fmaf(xv, w0.w, acc[j][3]);
        acc[j][4] = fmaf(xv, w1.x, acc[j][4]);
        acc[j][5] = fmaf(xv, w1.y, acc[j][5]);
        acc[j][6] = fmaf(xv, w1.z, acc[j][6]);
        acc[j][7] = fmaf(xv, w1.w, acc[j][7]);
      }
    }
  }

  #pragma unroll
  for (int j = 0; j < 4; ++j) {
    int gr = rowBase + r0 + j;
    if (gr < N) {
      float di = dis[gr];
      __half2 o[4];
      o[0] = __floats2half2_rn(di * acc[j][0], di * acc[j][1]);
      o[1] = __floats2half2_rn(di * acc[j][2], di * acc[j][3]);
      o[2] = __floats2half2_rn(di * acc[j][4], di * acc[j][5]);
      o[3] = __floats2half2_rn(di * acc[j][6], di * acc[j][7]);
      *(int4*)(P + (size_t)gr * NFEAT + cx) = *(const int4*)o;
    }
  }
}

// ---------------- aggregation: one wave/node, 4 edge-groups x 16 lanes, 16B/lane ----------------

__device__ __forceinline__ float agg_body(const __half* __restrict__ P,
                                          const int* __restrict__ rs,
                                          const int* __restrict__ csrc,
                                          int w, int g, int li, float acc[8]) {
  int e0 = rs[w], e1 = rs[w + 1];
  float di = rsqrtf((float)(e1 - e0) + 1.0f);
  if (g == 0) {  // self loop: P'[w]
    int4 raw = *(const int4*)(P + (size_t)w * NFEAT + li * 8);
    const __half2* h2 = (const __half2*)&raw;
    #pragma unroll
    for (int j = 0; j < 4; ++j) {
      float2 f = __half22float2(h2[j]);
      acc[2 * j]     = f.x;
      acc[2 * j + 1] = f.y;
    }
  }
  int e = e0 + g;
  int s = (e < e1) ? csrc[e] : 0;  // prefetched index
  while (e < e1) {
    int4 raw = *(const int4*)(P + (size_t)s * NFEAT + li * 8);
    e += 4;
    s = csrc[min(e, e1 - 1)];      // branchless prefetch of next index
    const __half2* h2 = (const __half2*)&raw;
    #pragma unroll
    for (int j = 0; j < 4; ++j) {
      float2 f = __half22float2(h2[j]);
      acc[2 * j]     += f.x;
      acc[2 * j + 1] += f.y;
    }
  }
  #pragma unroll
  for (int j = 0; j < 8; ++j) {
    float v = acc[j];
    v += __shfl_xor(v, 16, 64);
    v += __shfl_xor(v, 32, 64);
    acc[j] = v;
  }
  return di;
}

__global__ __launch_bounds__(256) void k_agg_relu(const __half* __restrict__ P,
                                                  const int* __restrict__ rs,
                                                  const int* __restrict__ csrc,
                                                  const float* __restrict__ bias,
                                                  __half* __restrict__ Hout, int N) {
  int w = (blockIdx.x * 256 + threadIdx.x) >> 6;
  if (w >= N) return;
  int lane = threadIdx.x & 63;
  int g = lane >> 4, li = lane & 15;
  float acc[8] = {0, 0, 0, 0, 0, 0, 0, 0};
  float di = agg_body(P, rs, csrc, w, g, li, acc);
  if (g == 0) {
    float4 b0 = *(const float4*)(bias + li * 8);
    float4 b1 = *(const float4*)(bias + li * 8 + 4);
    __half2 o[4];
    o[0] = __floats2half2_rn(fmaxf(fmaf(di, acc[0], b0.x), 0.f),
                             fmaxf(fmaf(di, acc[1], b0.y), 0.f));
    o[1] = __floats2half2_rn(fmaxf(fmaf(di, acc[2], b0.z), 0.f),
                             fmaxf(fmaf(di, acc[3], b0.w), 0.f));
    o[2] = __floats2half2_rn(fmaxf(fmaf(di, acc[4], b1.x), 0.f),
                             fmaxf(fmaf(di, acc[5], b1.y), 0.f));
    o[3] = __floats2half2_rn(fmaxf(fmaf(di, acc[6], b1.z), 0.f),
                             fmaxf(fmaf(di, acc[7], b1.w), 0.f));
    *(int4*)(Hout + (size_t)w * NFEAT + li * 8) = *(const int4*)o;
  }
}

__global__ __launch_bounds__(256) void k_agg_readout(const __half* __restrict__ P,
                                                     const int* __restrict__ rs,
                                                     const int* __restrict__ csrc,
                                                     const float* __restrict__ bias,
                                                     const float* __restrict__ Wout,
                                                     const float* __restrict__ bout,
                                                     float* __restrict__ out, int N) {
  int w = (blockIdx.x * 256 + threadIdx.x) >> 6;
  if (w >= N) return;
  int lane = threadIdx.x & 63;
  int g = lane >> 4, li = lane & 15;
  float acc[8] = {0, 0, 0, 0, 0, 0, 0, 0};
  float di = agg_body(P, rs, csrc, w, g, li, acc);
  float4 b0 = *(const float4*)(bias + li * 8);
  float4 b1 = *(const float4*)(bias + li * 8 + 4);
  float4 w0 = *(const float4*)(Wout + li * 8);
  float4 w1 = *(const float4*)(Wout + li * 8 + 4);
  float p = 0.f;
  p = fmaf(fmaxf(fmaf(di, acc[0], b0.x), 0.f), w0.x, p);
  p = fmaf(fmaxf(fmaf(di, acc[1], b0.y), 0.f), w0.y, p);
  p = fmaf(fmaxf(fmaf(di, acc[2], b0.z), 0.f), w0.z, p);
  p = fmaf(fmaxf(fmaf(di, acc[3], b0.w), 0.f), w0.w, p);
  p = fmaf(fmaxf(fmaf(di, acc[4], b1.x), 0.f), w1.x, p);
  p = fmaf(fmaxf(fmaf(di, acc[5], b1.y), 0.f), w1.y, p);
  p = fmaf(fmaxf(fmaf(di, acc[6], b1.z), 0.f), w1.z, p);
  p = fmaf(fmaxf(fmaf(di, acc[7], b1.w), 0.f), w1.w, p);
  p += __shfl_down(p, 8, 64);
  p += __shfl_down(p, 4, 64);
  p += __shfl_down(p, 2, 64);
  p += __shfl_down(p, 1, 64);
  if (lane == 0) out[w] = p + bout[0];
}

// ---------------- launch ----------------

extern "C" void kernel_launch(void* const* d_in, const int* in_sizes, int n_in,
                              void* d_out, int out_size, void* d_ws, size_t ws_size,
                              hipStream_t stream) {
  const float* x    = (const float*)d_in[0];
  const int*   ei   = (const int*)d_in[1];
  const float* W1   = (const float*)d_in[2];
  const float* b1   = (const float*)d_in[3];
  const float* W2   = (const float*)d_in[4];
  const float* b2   = (const float*)d_in[5];
  const float* Wout = (const float*)d_in[6];
  const float* bout = (const float*)d_in[7];
  float* out = (float*)d_out;

  const int N = in_sizes[0] / NFEAT;
  const int E = in_sizes[1] / 2;
  const int* src = ei;
  const int* dst = ei + E;
  const int NB = (N + 63) >> 6;  // 64-node buckets

  char* ws = (char*)d_ws;
  size_t off = 0;
  auto alloc = [&](size_t bytes) -> char* {
    char* p = ws + off;
    off = align_up(off + bytes, 256);
    return p;
  };
  int*      sb    = (int*)alloc((size_t)NB * 8 * 4);       // plane-major sub-counters
  int*      rsB   = (int*)alloc((size_t)(NB + 1) * 4);     // bucket bases
  int*      rs    = (int*)alloc((size_t)(N + 1) * 4);
  float*    dis   = (float*)alloc((size_t)N * 4);
  unsigned* ebuf  = (unsigned*)alloc((size_t)E * 4);       // bucket-grouped packed edges
  int*      csrc  = (int*)alloc((size_t)E * 4);
  __half*   P     = (__half*)alloc((size_t)N * NFEAT * 2);
  __half*   H     = (__half*)alloc((size_t)N * NFEAT * 2);
  (void)ws_size; (void)n_in; (void)out_size;

  const int nbE = (E + 255) / 256;

  hipMemsetAsync(sb, 0, (size_t)NB * 8 * 4, stream);
  k_count_sb<<<nbE, 256, 0, stream>>>(dst, sb, NB, E);
  k_scan_sb<<<1, 256, 0, stream>>>(sb, rsB, NB, E);
  k_bucket<<<nbE, 256, 0, stream>>>(src, dst, sb, ebuf, NB, E);
  k_fill3<<<NB, 256, 0, stream>>>(ebuf, rsB, rs, dis, csrc, N);

  k_gemm<float><<<(N + 63) / 64, 256, 0, stream>>>(x, W1, dis, P, N);
  k_agg_relu<<<(N + 3) / 4, 256, 0, stream>>>(P, rs, csrc, b1, H, N);
  k_gemm<__half><<<(N + 63) / 64, 256, 0, stream>>>(H, W2, dis, P, N);
  k_agg_readout<<<(N + 3) / 4, 256, 0, stream>>>(P, rs, csrc, b2, Wout, bout, out, N);
}

// Round 7
// 325.854 us; speedup vs baseline: 1.4681x; 1.2677x over previous
//
#include <hip/hip_runtime.h>
#include <hip/hip_fp16.h>
#include <type_traits>

#define NFEAT 128
// Node ids must fit 17 bits for the packed bucket entry (N=100000 < 2^17).
#define SRC_BITS 17
#define SRC_MASK ((1u << SRC_BITS) - 1u)
#define CHUNK 16384   // edges per sort block

static inline size_t align_up(size_t x, size_t a) { return (x + a - 1) & ~(a - 1); }

// ---------------- preprocessing: atomic-free counting sort ----------------

// per-block LDS histogram over 64-node buckets -> gh[blk][bucket]
__global__ __launch_bounds__(256) void k_hist(const int* __restrict__ dst,
                                              int* __restrict__ gh,
                                              int NBUK, int E) {
  extern __shared__ int h[];
  for (int i = threadIdx.x; i < NBUK; i += 256) h[i] = 0;
  __syncthreads();
  int base = blockIdx.x * CHUNK;
  int end = min(base + CHUNK, E);
  for (int e = base + threadIdx.x; e < end; e += 256)
    atomicAdd(&h[dst[e] >> 6], 1);
  __syncthreads();
  int* out = gh + (size_t)blockIdx.x * NBUK;
  for (int i = threadIdx.x; i < NBUK; i += 256) out[i] = h[i];
}

// per-bucket prefix over blocks (one thread per bucket, coalesced across buckets)
__global__ __launch_bounds__(256) void k_colscan(int* __restrict__ gh,
                                                 int* __restrict__ tot,
                                                 int NBUK, int nblk) {
  int b = blockIdx.x * 256 + threadIdx.x;
  if (b >= NBUK) return;
  int run = 0;
  for (int k = 0; k < nblk; ++k) {
    int idx = k * NBUK + b;
    int c = gh[idx];
    gh[idx] = run;
    run += c;
  }
  tot[b] = run;
}

// exclusive scan of bucket totals -> rsB[0..NBUK]
__global__ __launch_bounds__(256) void k_scanB(const int* __restrict__ tot,
                                               int* __restrict__ rsB,
                                               int NBUK, int E) {
  __shared__ int sd[256];
  int tid = threadIdx.x;
  int chunk = (NBUK + 255) / 256;
  int q0 = tid * chunk, q1 = min(q0 + chunk, NBUK);
  int sum = 0;
  for (int q = q0; q < q1; ++q) sum += tot[q];
  sd[tid] = sum;
  __syncthreads();
  for (int off = 1; off < 256; off <<= 1) {
    int t = (tid >= off) ? sd[tid - off] : 0;
    __syncthreads();
    sd[tid] += t;
    __syncthreads();
  }
  int run = sd[tid] - sum;
  for (int q = q0; q < q1; ++q) {
    int c = tot[q];
    rsB[q] = run;
    run += c;
  }
  if (tid == 255) rsB[NBUK] = E;
}

// scatter packed (dst&63)<<17|src to bucket-sorted ebuf; LDS cursors, no global atomics
__global__ __launch_bounds__(256) void k_scatter(const int* __restrict__ src,
                                                 const int* __restrict__ dst,
                                                 const int* __restrict__ gh,
                                                 const int* __restrict__ rsB,
                                                 unsigned* __restrict__ ebuf,
                                                 int NBUK, int E) {
  extern __shared__ int cur[];
  const int* g = gh + (size_t)blockIdx.x * NBUK;
  for (int i = threadIdx.x; i < NBUK; i += 256) cur[i] = rsB[i] + g[i];
  __syncthreads();
  int base = blockIdx.x * CHUNK;
  int end = min(base + CHUNK, E);
  for (int e = base + threadIdx.x; e < end; e += 256) {
    int d = dst[e];
    int pos = atomicAdd(&cur[d >> 6], 1);
    ebuf[pos] = (unsigned)src[e] | ((unsigned)(d & 63) << SRC_BITS);
  }
}

// per-bucket CSR build: LDS histogram -> rs + dis, LDS cursors -> csrc.
__global__ __launch_bounds__(256) void k_fill3(const unsigned* __restrict__ ebuf,
                                               const int* __restrict__ rsB,
                                               int* __restrict__ rs,
                                               float* __restrict__ dis,
                                               int* __restrict__ csrc, int N) {
  __shared__ int hist[64];
  __shared__ int curs[64];
  int b = blockIdx.x;
  int node0 = b << 6;
  int nn = min(64, N - node0);
  int base = rsB[b], end = rsB[b + 1];
  int tid = threadIdx.x;
  if (tid < 64) hist[tid] = 0;
  __syncthreads();
  for (int e = base + tid; e < end; e += 256)
    atomicAdd(&hist[ebuf[e] >> SRC_BITS], 1);
  __syncthreads();
  if (tid == 0) {
    int run = base;
    #pragma unroll
    for (int i = 0; i < 64; ++i) {
      int c = hist[i];
      curs[i] = run;
      hist[i] = run;
      run += c;
    }
  }
  __syncthreads();
  if (tid < nn) {
    int start = hist[tid];
    int nxt = (tid == nn - 1) ? end : hist[tid + 1];
    rs[node0 + tid] = start;
    dis[node0 + tid] = rsqrtf((float)(nxt - start) + 1.0f);
  }
  if (tid == 0) rs[node0 + nn] = end;
  for (int e = base + tid; e < end; e += 256) {
    unsigned u = ebuf[e];
    int pos = atomicAdd(&curs[u >> SRC_BITS], 1);
    csrc[pos] = (int)(u & SRC_MASK);
  }
}

// ---------------- GEMM: P[N x128] = dis[i] * (X[N x128] @ W[128 x128]), fp16 out ----------------

template <typename T>
__global__ __launch_bounds__(256) void k_gemm(const T* __restrict__ X,
                                              const float* __restrict__ W,
                                              const float* __restrict__ dis,
                                              __half* __restrict__ P, int N) {
  __shared__ float Xs[64][132];   // +4 pad
  __shared__ float Ws[64][128];
  const int tid = threadIdx.x;
  const int rowBase = blockIdx.x * 64;

  if constexpr (std::is_same_v<T, float>) {
    #pragma unroll
    for (int it = 0; it < 8; ++it) {
      int q = it * 256 + tid;
      int r = q >> 5;
      int c = (q & 31) * 4;
      int gr = rowBase + r;
      float4 v = make_float4(0.f, 0.f, 0.f, 0.f);
      if (gr < N) v = *(const float4*)(X + (size_t)gr * NFEAT + c);
      *(float4*)&Xs[r][c] = v;
    }
  } else {
    #pragma unroll
    for (int it = 0; it < 4; ++it) {
      int q = it * 256 + tid;
      int r = q >> 4;
      int c = (q & 15) * 8;
      int gr = rowBase + r;
      int4 raw = make_int4(0, 0, 0, 0);
      if (gr < N) raw = *(const int4*)(X + (size_t)gr * NFEAT + c);
      const __half2* h2 = (const __half2*)&raw;
      #pragma unroll
      for (int j = 0; j < 4; ++j) {
        float2 f = __half22float2(h2[j]);
        Xs[r][c + 2 * j] = f.x;
        Xs[r][c + 2 * j + 1] = f.y;
      }
    }
  }

  float acc[4][8];
  #pragma unroll
  for (int j = 0; j < 4; ++j)
    #pragma unroll
    for (int c = 0; c < 8; ++c) acc[j][c] = 0.f;

  const int cx = (tid & 15) * 8;
  const int r0 = (tid >> 4) * 4;

  for (int half = 0; half < 2; ++half) {
    __syncthreads();
    #pragma unroll
    for (int it = 0; it < 8; ++it) {
      int q = it * 256 + tid;
      int r = q >> 5;
      int c = (q & 31) * 4;
      *(float4*)&Ws[r][c] = *(const float4*)(W + (size_t)(half * 64 + r) * NFEAT + c);
    }
    __syncthreads();
    #pragma unroll 4
    for (int k = 0; k < 64; ++k) {
      float4 w0 = *(const float4*)&Ws[k][cx];
      float4 w1 = *(const float4*)&Ws[k][cx + 4];
      int kg = half * 64 + k;
      #pragma unroll
      for (int j = 0; j < 4; ++j) {
        float xv = Xs[r0 + j][kg];
        acc[j][0] = fmaf(xv, w0.x, acc[j][0]);
        acc[j][1] = fmaf(xv, w0.y, acc[j][1]);
        acc[j][2] = fmaf(xv, w0.z, acc[j][2]);
        acc[j][3] = fmaf(xv, w0.w, acc[j][3]);
        acc[j][4] = fmaf(xv, w1.x, acc[j][4]);
        acc[j][5] = fmaf(xv, w1.y, acc[j][5]);
        acc[j][6] = fmaf(xv, w1.z, acc[j][6]);
        acc[j][7] = fmaf(xv, w1.w, acc[j][7]);
      }
    }
  }

  #pragma unroll
  for (int j = 0; j < 4; ++j) {
    int gr = rowBase + r0 + j;
    if (gr < N) {
      float di = dis[gr];
      __half2 o[4];
      o[0] = __floats2half2_rn(di * acc[j][0], di * acc[j][1]);
      o[1] = __floats2half2_rn(di * acc[j][2], di * acc[j][3]);
      o[2] = __floats2half2_rn(di * acc[j][4], di * acc[j][5]);
      o[3] = __floats2half2_rn(di * acc[j][6], di * acc[j][7]);
      *(int4*)(P + (size_t)gr * NFEAT + cx) = *(const int4*)o;
    }
  }
}

// ---------------- aggregation: one wave/node, 4 edge-groups x 16 lanes, 16B/lane ----------------

__device__ __forceinline__ float agg_body(const __half* __restrict__ P,
                                          const int* __restrict__ rs,
                                          const int* __restrict__ csrc,
                                          int w, int g, int li, float acc[8]) {
  int e0 = rs[w], e1 = rs[w + 1];
  float di = rsqrtf((float)(e1 - e0) + 1.0f);
  if (g == 0) {  // self loop: P'[w]
    int4 raw = *(const int4*)(P + (size_t)w * NFEAT + li * 8);
    const __half2* h2 = (const __half2*)&raw;
    #pragma unroll
    for (int j = 0; j < 4; ++j) {
      float2 f = __half22float2(h2[j]);
      acc[2 * j]     = f.x;
      acc[2 * j + 1] = f.y;
    }
  }
  int e = e0 + g;
  int s = (e < e1) ? csrc[e] : 0;  // prefetched index
  while (e < e1) {
    int4 raw = *(const int4*)(P + (size_t)s * NFEAT + li * 8);
    e += 4;
    s = csrc[min(e, e1 - 1)];      // branchless prefetch of next index
    const __half2* h2 = (const __half2*)&raw;
    #pragma unroll
    for (int j = 0; j < 4; ++j) {
      float2 f = __half22float2(h2[j]);
      acc[2 * j]     += f.x;
      acc[2 * j + 1] += f.y;
    }
  }
  #pragma unroll
  for (int j = 0; j < 8; ++j) {
    float v = acc[j];
    v += __shfl_xor(v, 16, 64);
    v += __shfl_xor(v, 32, 64);
    acc[j] = v;
  }
  return di;
}

__global__ __launch_bounds__(256) void k_agg_relu(const __half* __restrict__ P,
                                                  const int* __restrict__ rs,
                                                  const int* __restrict__ csrc,
                                                  const float* __restrict__ bias,
                                                  __half* __restrict__ Hout, int N) {
  int w = (blockIdx.x * 256 + threadIdx.x) >> 6;
  if (w >= N) return;
  int lane = threadIdx.x & 63;
  int g = lane >> 4, li = lane & 15;
  float acc[8] = {0, 0, 0, 0, 0, 0, 0, 0};
  float di = agg_body(P, rs, csrc, w, g, li, acc);
  if (g == 0) {
    float4 b0 = *(const float4*)(bias + li * 8);
    float4 b1 = *(const float4*)(bias + li * 8 + 4);
    __half2 o[4];
    o[0] = __floats2half2_rn(fmaxf(fmaf(di, acc[0], b0.x), 0.f),
                             fmaxf(fmaf(di, acc[1], b0.y), 0.f));
    o[1] = __floats2half2_rn(fmaxf(fmaf(di, acc[2], b0.z), 0.f),
                             fmaxf(fmaf(di, acc[3], b0.w), 0.f));
    o[2] = __floats2half2_rn(fmaxf(fmaf(di, acc[4], b1.x), 0.f),
                             fmaxf(fmaf(di, acc[5], b1.y), 0.f));
    o[3] = __floats2half2_rn(fmaxf(fmaf(di, acc[6], b1.z), 0.f),
                             fmaxf(fmaf(di, acc[7], b1.w), 0.f));
    *(int4*)(Hout + (size_t)w * NFEAT + li * 8) = *(const int4*)o;
  }
}

__global__ __launch_bounds__(256) void k_agg_readout(const __half* __restrict__ P,
                                                     const int* __restrict__ rs,
                                                     const int* __restrict__ csrc,
                                                     const float* __restrict__ bias,
                                                     const float* __restrict__ Wout,
                                                     const float* __restrict__ bout,
                                                     float* __restrict__ out, int N) {
  int w = (blockIdx.x * 256 + threadIdx.x) >> 6;
  if (w >= N) return;
  int lane = threadIdx.x & 63;
  int g = lane >> 4, li = lane & 15;
  float acc[8] = {0, 0, 0, 0, 0, 0, 0, 0};
  float di = agg_body(P, rs, csrc, w, g, li, acc);
  float4 b0 = *(const float4*)(bias + li * 8);
  float4 b1 = *(const float4*)(bias + li * 8 + 4);
  float4 w0 = *(const float4*)(Wout + li * 8);
  float4 w1 = *(const float4*)(Wout + li * 8 + 4);
  float p = 0.f;
  p = fmaf(fmaxf(fmaf(di, acc[0], b0.x), 0.f), w0.x, p);
  p = fmaf(fmaxf(fmaf(di, acc[1], b0.y), 0.f), w0.y, p);
  p = fmaf(fmaxf(fmaf(di, acc[2], b0.z), 0.f), w0.z, p);
  p = fmaf(fmaxf(fmaf(di, acc[3], b0.w), 0.f), w0.w, p);
  p = fmaf(fmaxf(fmaf(di, acc[4], b1.x), 0.f), w1.x, p);
  p = fmaf(fmaxf(fmaf(di, acc[5], b1.y), 0.f), w1.y, p);
  p = fmaf(fmaxf(fmaf(di, acc[6], b1.z), 0.f), w1.z, p);
  p = fmaf(fmaxf(fmaf(di, acc[7], b1.w), 0.f), w1.w, p);
  p += __shfl_down(p, 8, 64);
  p += __shfl_down(p, 4, 64);
  p += __shfl_down(p, 2, 64);
  p += __shfl_down(p, 1, 64);
  if (lane == 0) out[w] = p + bout[0];
}

// ---------------- launch ----------------

extern "C" void kernel_launch(void* const* d_in, const int* in_sizes, int n_in,
                              void* d_out, int out_size, void* d_ws, size_t ws_size,
                              hipStream_t stream) {
  const float* x    = (const float*)d_in[0];
  const int*   ei   = (const int*)d_in[1];
  const float* W1   = (const float*)d_in[2];
  const float* b1   = (const float*)d_in[3];
  const float* W2   = (const float*)d_in[4];
  const float* b2   = (const float*)d_in[5];
  const float* Wout = (const float*)d_in[6];
  const float* bout = (const float*)d_in[7];
  float* out = (float*)d_out;

  const int N = in_sizes[0] / NFEAT;
  const int E = in_sizes[1] / 2;
  const int* src = ei;
  const int* dst = ei + E;
  const int NBUK = (N + 63) >> 6;          // 64-node buckets (1563)
  const int nblk = (E + CHUNK - 1) / CHUNK; // sort blocks (98)

  char* ws = (char*)d_ws;
  size_t off = 0;
  auto alloc = [&](size_t bytes) -> char* {
    char* p = ws + off;
    off = align_up(off + bytes, 256);
    return p;
  };
  int*      gh    = (int*)alloc((size_t)nblk * NBUK * 4);  // per-block bucket counts
  int*      tot   = (int*)alloc((size_t)NBUK * 4);
  int*      rsB   = (int*)alloc((size_t)(NBUK + 1) * 4);
  int*      rs    = (int*)alloc((size_t)(N + 1) * 4);
  float*    dis   = (float*)alloc((size_t)N * 4);
  unsigned* ebuf  = (unsigned*)alloc((size_t)E * 4);
  int*      csrc  = (int*)alloc((size_t)E * 4);
  __half*   P     = (__half*)alloc((size_t)N * NFEAT * 2);
  __half*   H     = (__half*)alloc((size_t)N * NFEAT * 2);
  (void)ws_size; (void)n_in; (void)out_size;

  const size_t ldsBuk = (size_t)NBUK * 4;

  k_hist<<<nblk, 256, ldsBuk, stream>>>(dst, gh, NBUK, E);
  k_colscan<<<(NBUK + 255) / 256, 256, 0, stream>>>(gh, tot, NBUK, nblk);
  k_scanB<<<1, 256, 0, stream>>>(tot, rsB, NBUK, E);
  k_scatter<<<nblk, 256, ldsBuk, stream>>>(src, dst, gh, rsB, ebuf, NBUK, E);
  k_fill3<<<NBUK, 256, 0, stream>>>(ebuf, rsB, rs, dis, csrc, N);

  k_gemm<float><<<(N + 63) / 64, 256, 0, stream>>>(x, W1, dis, P, N);
  k_agg_relu<<<(N + 3) / 4, 256, 0, stream>>>(P, rs, csrc, b1, H, N);
  k_gemm<__half><<<(N + 63) / 64, 256, 0, stream>>>(H, W2, dis, P, N);
  k_agg_readout<<<(N + 3) / 4, 256, 0, stream>>>(P, rs, csrc, b2, Wout, bout, out, N);
}

// Round 8
// 281.588 us; speedup vs baseline: 1.6989x; 1.1572x over previous
//
#include <hip/hip_runtime.h>
#include <hip/hip_fp16.h>
#include <type_traits>

#define NFEAT 128
// Node ids must fit 17 bits for the packed bucket entry (N=100000 < 2^17).
#define SRC_BITS 17
#define SRC_MASK ((1u << SRC_BITS) - 1u)
#define CHUNK 8192    // edges per sort block
#define STHREADS 512  // threads for hist/scatter

using f16x8 = __attribute__((ext_vector_type(8))) _Float16;
using f32x4 = __attribute__((ext_vector_type(4))) float;

static inline size_t align_up(size_t x, size_t a) { return (x + a - 1) & ~(a - 1); }

// ---------------- preprocessing: atomic-free counting sort ----------------

__global__ __launch_bounds__(STHREADS) void k_hist(const int* __restrict__ dst,
                                                   int* __restrict__ gh,
                                                   int NBUK, int E) {
  extern __shared__ int h[];
  for (int i = threadIdx.x; i < NBUK; i += STHREADS) h[i] = 0;
  __syncthreads();
  int base = blockIdx.x * CHUNK;
  int end = min(base + CHUNK, E);
  for (int e = base + threadIdx.x; e < end; e += STHREADS)
    atomicAdd(&h[dst[e] >> 6], 1);
  __syncthreads();
  int* out = gh + (size_t)blockIdx.x * NBUK;
  for (int i = threadIdx.x; i < NBUK; i += STHREADS) out[i] = h[i];
}

// per-bucket prefix over blocks (one thread per bucket, coalesced across buckets)
__global__ __launch_bounds__(256) void k_colscan(int* __restrict__ gh,
                                                 int* __restrict__ tot,
                                                 int NBUK, int nblk) {
  int b = blockIdx.x * 256 + threadIdx.x;
  if (b >= NBUK) return;
  int run = 0;
  for (int k = 0; k < nblk; ++k) {
    int idx = k * NBUK + b;
    int c = gh[idx];
    gh[idx] = run;
    run += c;
  }
  tot[b] = run;
}

__global__ __launch_bounds__(256) void k_scanB(const int* __restrict__ tot,
                                               int* __restrict__ rsB,
                                               int NBUK, int E) {
  __shared__ int sd[256];
  int tid = threadIdx.x;
  int chunk = (NBUK + 255) / 256;
  int q0 = tid * chunk, q1 = min(q0 + chunk, NBUK);
  int sum = 0;
  for (int q = q0; q < q1; ++q) sum += tot[q];
  sd[tid] = sum;
  __syncthreads();
  for (int off = 1; off < 256; off <<= 1) {
    int t = (tid >= off) ? sd[tid - off] : 0;
    __syncthreads();
    sd[tid] += t;
    __syncthreads();
  }
  int run = sd[tid] - sum;
  for (int q = q0; q < q1; ++q) {
    int c = tot[q];
    rsB[q] = run;
    run += c;
  }
  if (tid == 255) rsB[NBUK] = E;
}

// scatter packed (dst&63)<<17|src to bucket-sorted ebuf; LDS cursors, no global atomics
__global__ __launch_bounds__(STHREADS) void k_scatter(const int* __restrict__ src,
                                                      const int* __restrict__ dst,
                                                      const int* __restrict__ gh,
                                                      const int* __restrict__ rsB,
                                                      unsigned* __restrict__ ebuf,
                                                      int NBUK, int E) {
  extern __shared__ int cur[];
  const int* g = gh + (size_t)blockIdx.x * NBUK;
  for (int i = threadIdx.x; i < NBUK; i += STHREADS) cur[i] = rsB[i] + g[i];
  __syncthreads();
  int base = blockIdx.x * CHUNK;
  int end = min(base + CHUNK, E);
  for (int e = base + threadIdx.x; e < end; e += STHREADS) {
    int d = dst[e];
    int pos = atomicAdd(&cur[d >> 6], 1);
    ebuf[pos] = (unsigned)src[e] | ((unsigned)(d & 63) << SRC_BITS);
  }
}

// per-bucket CSR build: LDS histogram -> rs + dis, LDS cursors -> csrc.
__global__ __launch_bounds__(256) void k_fill3(const unsigned* __restrict__ ebuf,
                                               const int* __restrict__ rsB,
                                               int* __restrict__ rs,
                                               float* __restrict__ dis,
                                               int* __restrict__ csrc, int N) {
  __shared__ int hist[64];
  __shared__ int curs[64];
  int b = blockIdx.x;
  int node0 = b << 6;
  int nn = min(64, N - node0);
  int base = rsB[b], end = rsB[b + 1];
  int tid = threadIdx.x;
  if (tid < 64) hist[tid] = 0;
  __syncthreads();
  for (int e = base + tid; e < end; e += 256)
    atomicAdd(&hist[ebuf[e] >> SRC_BITS], 1);
  __syncthreads();
  if (tid == 0) {
    int run = base;
    #pragma unroll
    for (int i = 0; i < 64; ++i) {
      int c = hist[i];
      curs[i] = run;
      hist[i] = run;
      run += c;
    }
  }
  __syncthreads();
  if (tid < nn) {
    int start = hist[tid];
    int nxt = (tid == nn - 1) ? end : hist[tid + 1];
    rs[node0 + tid] = start;
    dis[node0 + tid] = rsqrtf((float)(nxt - start) + 1.0f);
  }
  if (tid == 0) rs[node0 + nn] = end;
  for (int e = base + tid; e < end; e += 256) {
    unsigned u = ebuf[e];
    int pos = atomicAdd(&curs[u >> SRC_BITS], 1);
    csrc[pos] = (int)(u & SRC_MASK);
  }
}

// ---------------- W transpose to fp16: Wt[j][k] = W[k][j] ----------------

__global__ __launch_bounds__(256) void k_wt(const float* __restrict__ W,
                                            __half* __restrict__ Wt) {
  int t = threadIdx.x;
  for (int i = 0; i < 64; ++i) {
    int e = i * 256 + t;
    int r = e >> 7, c = e & 127;
    Wt[c * 128 + r] = __float2half(W[e]);
  }
}

// ---------------- MFMA GEMM: P[N x128] = dis[i]*(X @ W), fp16 frag, fp32 acc ----------------
// Block: 64 rows x 128 cols, K=128 fully in LDS. 4 waves; wave w owns cols w*32..w*32+31.
// A-frag: X[row=lane&15][k=(lane>>4)*8+j]; B-frag: Wt[col][same k]; D[row=(lane>>4)*4+r][col=lane&15].

#define XS_LD 136  // halves; 272B row stride -> 2-way (free) bank aliasing on b128

template <typename T>
__global__ __launch_bounds__(256) void k_gemm(const T* __restrict__ X,
                                              const __half* __restrict__ Wt,
                                              const float* __restrict__ dis,
                                              __half* __restrict__ P, int N) {
  __shared__ __half Xs[64 * XS_LD];
  __shared__ __half Ws[128 * XS_LD];
  const int tid = threadIdx.x;
  const int wave = tid >> 6, lane = tid & 63;
  const int l15 = lane & 15, g = lane >> 4;
  const int rowBase = blockIdx.x * 64;

  // stage Wt (128 rows x 128 halves)
  #pragma unroll
  for (int it = 0; it < 8; ++it) {
    int q = it * 256 + tid;
    int r = q >> 4, c = (q & 15) * 8;
    *(int4*)&Ws[r * XS_LD + c] = *(const int4*)(Wt + r * 128 + c);
  }
  // stage X tile (convert fp32 -> fp16 if needed)
  if constexpr (std::is_same_v<T, float>) {
    #pragma unroll
    for (int it = 0; it < 8; ++it) {
      int q = it * 256 + tid;
      int r = q >> 5, c = (q & 31) * 4;
      int gr = rowBase + r;
      float4 v = make_float4(0.f, 0.f, 0.f, 0.f);
      if (gr < N) v = *(const float4*)(X + (size_t)gr * NFEAT + c);
      __half2 pk[2];
      pk[0] = __floats2half2_rn(v.x, v.y);
      pk[1] = __floats2half2_rn(v.z, v.w);
      *(uint2*)&Xs[r * XS_LD + c] = *(uint2*)pk;
    }
  } else {
    #pragma unroll
    for (int it = 0; it < 4; ++it) {
      int q = it * 256 + tid;
      int r = q >> 4, c = (q & 15) * 8;
      int gr = rowBase + r;
      int4 v = make_int4(0, 0, 0, 0);
      if (gr < N) v = *(const int4*)(X + (size_t)gr * NFEAT + c);
      *(int4*)&Xs[r * XS_LD + c] = v;
    }
  }
  __syncthreads();

  f32x4 acc[4][2];
  #pragma unroll
  for (int rt = 0; rt < 4; ++rt) {
    acc[rt][0] = (f32x4)(0.f);
    acc[rt][1] = (f32x4)(0.f);
  }
  const int koff = g * 8;
  const int c0 = (wave * 2) * 16 + l15;
  const int c1 = (wave * 2 + 1) * 16 + l15;

  #pragma unroll
  for (int ks = 0; ks < 4; ++ks) {
    int kb = ks * 32 + koff;
    f16x8 b0 = *(const f16x8*)&Ws[c0 * XS_LD + kb];
    f16x8 b1 = *(const f16x8*)&Ws[c1 * XS_LD + kb];
    #pragma unroll
    for (int rt = 0; rt < 4; ++rt) {
      f16x8 a = *(const f16x8*)&Xs[(rt * 16 + l15) * XS_LD + kb];
      acc[rt][0] = __builtin_amdgcn_mfma_f32_16x16x32_f16(a, b0, acc[rt][0], 0, 0, 0);
      acc[rt][1] = __builtin_amdgcn_mfma_f32_16x16x32_f16(a, b1, acc[rt][1], 0, 0, 0);
    }
  }

  const int colb = wave * 32 + l15;
  #pragma unroll
  for (int rt = 0; rt < 4; ++rt) {
    #pragma unroll
    for (int r = 0; r < 4; ++r) {
      int row = rowBase + rt * 16 + g * 4 + r;
      if (row < N) {
        float di = dis[row];
        P[(size_t)row * NFEAT + colb]      = __float2half(di * acc[rt][0][r]);
        P[(size_t)row * NFEAT + colb + 16] = __float2half(di * acc[rt][1][r]);
      }
    }
  }
}

// ---------------- aggregation: one wave/node, 4 edge-groups x 16 lanes, 16B/lane ----------------

__device__ __forceinline__ float agg_body(const __half* __restrict__ P,
                                          const int* __restrict__ rs,
                                          const int* __restrict__ csrc,
                                          int w, int g, int li, float acc[8]) {
  int e0 = rs[w], e1 = rs[w + 1];
  float di = rsqrtf((float)(e1 - e0) + 1.0f);
  if (g == 0) {  // self loop: P'[w]
    int4 raw = *(const int4*)(P + (size_t)w * NFEAT + li * 8);
    const __half2* h2 = (const __half2*)&raw;
    #pragma unroll
    for (int j = 0; j < 4; ++j) {
      float2 f = __half22float2(h2[j]);
      acc[2 * j]     = f.x;
      acc[2 * j + 1] = f.y;
    }
  }
  int e = e0 + g;
  int s = (e < e1) ? csrc[e] : 0;  // prefetched index
  while (e < e1) {
    int4 raw = *(const int4*)(P + (size_t)s * NFEAT + li * 8);
    e += 4;
    s = csrc[min(e, e1 - 1)];      // branchless prefetch of next index
    const __half2* h2 = (const __half2*)&raw;
    #pragma unroll
    for (int j = 0; j < 4; ++j) {
      float2 f = __half22float2(h2[j]);
      acc[2 * j]     += f.x;
      acc[2 * j + 1] += f.y;
    }
  }
  #pragma unroll
  for (int j = 0; j < 8; ++j) {
    float v = acc[j];
    v += __shfl_xor(v, 16, 64);
    v += __shfl_xor(v, 32, 64);
    acc[j] = v;
  }
  return di;
}

__global__ __launch_bounds__(256) void k_agg_relu(const __half* __restrict__ P,
                                                  const int* __restrict__ rs,
                                                  const int* __restrict__ csrc,
                                                  const float* __restrict__ bias,
                                                  __half* __restrict__ Hout, int N) {
  int w = (blockIdx.x * 256 + threadIdx.x) >> 6;
  if (w >= N) return;
  int lane = threadIdx.x & 63;
  int g = lane >> 4, li = lane & 15;
  float acc[8] = {0, 0, 0, 0, 0, 0, 0, 0};
  float di = agg_body(P, rs, csrc, w, g, li, acc);
  if (g == 0) {
    float4 b0 = *(const float4*)(bias + li * 8);
    float4 b1 = *(const float4*)(bias + li * 8 + 4);
    __half2 o[4];
    o[0] = __floats2half2_rn(fmaxf(fmaf(di, acc[0], b0.x), 0.f),
                             fmaxf(fmaf(di, acc[1], b0.y), 0.f));
    o[1] = __floats2half2_rn(fmaxf(fmaf(di, acc[2], b0.z), 0.f),
                             fmaxf(fmaf(di, acc[3], b0.w), 0.f));
    o[2] = __floats2half2_rn(fmaxf(fmaf(di, acc[4], b1.x), 0.f),
                             fmaxf(fmaf(di, acc[5], b1.y), 0.f));
    o[3] = __floats2half2_rn(fmaxf(fmaf(di, acc[6], b1.z), 0.f),
                             fmaxf(fmaf(di, acc[7], b1.w), 0.f));
    *(int4*)(Hout + (size_t)w * NFEAT + li * 8) = *(const int4*)o;
  }
}

__global__ __launch_bounds__(256) void k_agg_readout(const __half* __restrict__ P,
                                                     const int* __restrict__ rs,
                                                     const int* __restrict__ csrc,
                                                     const float* __restrict__ bias,
                                                     const float* __restrict__ Wout,
                                                     const float* __restrict__ bout,
                                                     float* __restrict__ out, int N) {
  int w = (blockIdx.x * 256 + threadIdx.x) >> 6;
  if (w >= N) return;
  int lane = threadIdx.x & 63;
  int g = lane >> 4, li = lane & 15;
  float acc[8] = {0, 0, 0, 0, 0, 0, 0, 0};
  float di = agg_body(P, rs, csrc, w, g, li, acc);
  float4 b0 = *(const float4*)(bias + li * 8);
  float4 b1 = *(const float4*)(bias + li * 8 + 4);
  float4 w0 = *(const float4*)(Wout + li * 8);
  float4 w1 = *(const float4*)(Wout + li * 8 + 4);
  float p = 0.f;
  p = fmaf(fmaxf(fmaf(di, acc[0], b0.x), 0.f), w0.x, p);
  p = fmaf(fmaxf(fmaf(di, acc[1], b0.y), 0.f), w0.y, p);
  p = fmaf(fmaxf(fmaf(di, acc[2], b0.z), 0.f), w0.z, p);
  p = fmaf(fmaxf(fmaf(di, acc[3], b0.w), 0.f), w0.w, p);
  p = fmaf(fmaxf(fmaf(di, acc[4], b1.x), 0.f), w1.x, p);
  p = fmaf(fmaxf(fmaf(di, acc[5], b1.y), 0.f), w1.y, p);
  p = fmaf(fmaxf(fmaf(di, acc[6], b1.z), 0.f), w1.z, p);
  p = fmaf(fmaxf(fmaf(di, acc[7], b1.w), 0.f), w1.w, p);
  p += __shfl_down(p, 8, 64);
  p += __shfl_down(p, 4, 64);
  p += __shfl_down(p, 2, 64);
  p += __shfl_down(p, 1, 64);
  if (lane == 0) out[w] = p + bout[0];
}

// ---------------- launch ----------------

extern "C" void kernel_launch(void* const* d_in, const int* in_sizes, int n_in,
                              void* d_out, int out_size, void* d_ws, size_t ws_size,
                              hipStream_t stream) {
  const float* x    = (const float*)d_in[0];
  const int*   ei   = (const int*)d_in[1];
  const float* W1   = (const float*)d_in[2];
  const float* b1   = (const float*)d_in[3];
  const float* W2   = (const float*)d_in[4];
  const float* b2   = (const float*)d_in[5];
  const float* Wout = (const float*)d_in[6];
  const float* bout = (const float*)d_in[7];
  float* out = (float*)d_out;

  const int N = in_sizes[0] / NFEAT;
  const int E = in_sizes[1] / 2;
  const int* src = ei;
  const int* dst = ei + E;
  const int NBUK = (N + 63) >> 6;           // 64-node buckets (1563)
  const int nblk = (E + CHUNK - 1) / CHUNK; // sort blocks (196)

  char* ws = (char*)d_ws;
  size_t off = 0;
  auto alloc = [&](size_t bytes) -> char* {
    char* p = ws + off;
    off = align_up(off + bytes, 256);
    return p;
  };
  int*      gh    = (int*)alloc((size_t)nblk * NBUK * 4);
  int*      tot   = (int*)alloc((size_t)NBUK * 4);
  int*      rsB   = (int*)alloc((size_t)(NBUK + 1) * 4);
  int*      rs    = (int*)alloc((size_t)(N + 1) * 4);
  float*    dis   = (float*)alloc((size_t)N * 4);
  unsigned* ebuf  = (unsigned*)alloc((size_t)E * 4);
  int*      csrc  = (int*)alloc((size_t)E * 4);
  __half*   W1t   = (__half*)alloc((size_t)NFEAT * NFEAT * 2);
  __half*   W2t   = (__half*)alloc((size_t)NFEAT * NFEAT * 2);
  __half*   P     = (__half*)alloc((size_t)N * NFEAT * 2);
  __half*   H     = (__half*)alloc((size_t)N * NFEAT * 2);
  (void)ws_size; (void)n_in; (void)out_size;

  const size_t ldsBuk = (size_t)NBUK * 4;

  k_wt<<<1, 256, 0, stream>>>(W1, W1t);
  k_wt<<<1, 256, 0, stream>>>(W2, W2t);
  k_hist<<<nblk, STHREADS, ldsBuk, stream>>>(dst, gh, NBUK, E);
  k_colscan<<<(NBUK + 255) / 256, 256, 0, stream>>>(gh, tot, NBUK, nblk);
  k_scanB<<<1, 256, 0, stream>>>(tot, rsB, NBUK, E);
  k_scatter<<<nblk, STHREADS, ldsBuk, stream>>>(src, dst, gh, rsB, ebuf, NBUK, E);
  k_fill3<<<NBUK, 256, 0, stream>>>(ebuf, rsB, rs, dis, csrc, N);

  k_gemm<float><<<(N + 63) / 64, 256, 0, stream>>>(x, W1t, dis, P, N);
  k_agg_relu<<<(N + 3) / 4, 256, 0, stream>>>(P, rs, csrc, b1, H, N);
  k_gemm<__half><<<(N + 63) / 64, 256, 0, stream>>>(H, W2t, dis, P, N);
  k_agg_readout<<<(N + 3) / 4, 256, 0, stream>>>(P, rs, csrc, b2, Wout, bout, out, N);
}